// Round 4
// baseline (393.539 us; speedup 1.0000x reference)
//
#include <hip/hip_runtime.h>
#include <hip/hip_cooperative_groups.h>

namespace cg = cooperative_groups;

#define N_NODES  50000
#define N_EDGES  800000
#define N_GRAPHS 512
#define HID      64
#define NCLS     5
#define NB       64      // bucket capacity per node (max deg ~40 for this graph)
#define EST      36      // LDS embed row stride in uints
#define AST      68      // LDS As row stride in uints (64 data + 4 pad)
#define NPB      32      // nodes per block-iteration (R3 structure)
#define NGRP     ((N_NODES + NPB - 1) / NPB)   // 1563
#define EBUF_T   (128 * 32)
#define PW_T     (64 * 64)

typedef __attribute__((ext_vector_type(8))) short bf16x8;
typedef __attribute__((ext_vector_type(4))) float f32x4;

__device__ inline unsigned short f2bf(float f) {
    unsigned int u = __builtin_bit_cast(unsigned int, f);
    unsigned int r = (u + 0x7FFFu + ((u >> 16) & 1u)) >> 16;   // RNE
    return (unsigned short)r;
}
__device__ inline unsigned int packbf(float a, float b) {
    return (unsigned int)f2bf(a) | ((unsigned int)f2bf(b) << 16);
}
__device__ inline float bf2f(unsigned int u16) {
    unsigned int t = u16 << 16;
    return __builtin_bit_cast(float, t);
}

struct KParams {
    const int *src, *dst, *tok, *batch;
    const float *embed, *W1l, *b1l, *W1r, *W2l, *b2l, *W2r, *Wlin, *blin;
    int *cnt, *pstart, *pend;
    unsigned int *bucket, *x1b, *x2b, *wb1, *wb2;
    float *out;
};

// ---- layer phase (R3's k_layer body in a grid-stride loop over node groups) ----
__device__ __forceinline__ void layer_phase(
    bool L1, const int* cnt, const unsigned int* bucket,
    const int* tok, const unsigned int* xb,
    const unsigned int* wb, const float* bl, unsigned short* xoutb,
    unsigned int* As, const unsigned int* elds, int bid, int gsz, int tid)
{
    const int wv   = tid >> 6;        // 0..7
    const int lane = tid & 63;
    const int q    = lane & 7;        // 16B chunk (channels 8q..8q+7)
    const int e8   = lane >> 3;       // edge slot within group of 8

    for (int grp = bid; grp < NGRP; grp += gsz) {
        const int n0 = grp * NPB;
#pragma unroll
        for (int i = 0; i < 4; ++i) {
            int rl = wv * 4 + i;          // local row 0..31
            int nn = n0 + rl;
            int nc = min(nn, N_NODES - 1);
            int deg = cnt[nc];
            int m   = (nn < N_NODES) ? min(deg, NB) : 0;
            unsigned int v = (lane < m) ? bucket[(long)nc * NB + lane] : 0u;
            float f0 = 0, f1 = 0, f2 = 0, f3 = 0, f4 = 0, f5 = 0, f6 = 0, f7 = 0;
#pragma unroll
            for (int g = 0; g < 8; ++g) {
                int j = g * 8 + e8;
                unsigned int vv = __shfl(v, j, 64);
                if (j < m) {
                    uint4 w4;
                    if (L1) w4 = *(const uint4*)(elds + (vv >> 16) * EST + q * 4);
                    else    w4 = *((const uint4*)(xb + (long)(vv & 0xffffu) * 32) + q);
                    f0 += bf2f(w4.x & 0xffff); f1 += bf2f(w4.x >> 16);
                    f2 += bf2f(w4.y & 0xffff); f3 += bf2f(w4.y >> 16);
                    f4 += bf2f(w4.z & 0xffff); f5 += bf2f(w4.z >> 16);
                    f6 += bf2f(w4.w & 0xffff); f7 += bf2f(w4.w >> 16);
                }
            }
#pragma unroll
            for (int o = 8; o < 64; o <<= 1) {
                f0 += __shfl_xor(f0, o, 64); f1 += __shfl_xor(f1, o, 64);
                f2 += __shfl_xor(f2, o, 64); f3 += __shfl_xor(f3, o, 64);
                f4 += __shfl_xor(f4, o, 64); f5 += __shfl_xor(f5, o, 64);
                f6 += __shfl_xor(f6, o, 64); f7 += __shfl_xor(f7, o, 64);
            }
            if (e8 == 0) {
                float inv = 1.0f / (float)max(deg, 1);
                uint4 o;
                o.x = packbf(f0 * inv, f1 * inv);
                o.y = packbf(f2 * inv, f3 * inv);
                o.z = packbf(f4 * inv, f5 * inv);
                o.w = packbf(f6 * inv, f7 * inv);
                *(uint4*)(As + rl * AST + q * 4) = o;
            } else if (e8 == 1) {
                uint4 sv;
                if (L1) { int tk = tok[nc]; sv = *(const uint4*)(elds + tk * EST + q * 4); }
                else    { sv = *((const uint4*)(xb + (long)nc * 32) + q); }
                *(uint4*)(As + rl * AST + 32 + q * 4) = sv;
            }
        }
        __syncthreads();

        // Phase B: wave wv -> strip s = wv&1 (16 nodes), h-tile t = wv>>1
        const int s    = wv & 1;
        const int t    = wv >> 1;
        const int mm   = lane & 15;
        const int quad = lane >> 4;

        bf16x8 afr[4];
#pragma unroll
        for (int kst = 0; kst < 4; ++kst)
            afr[kst] = *(const bf16x8*)(As + (s * 16 + mm) * AST + kst * 16 + quad * 4);

        f32x4 acc = (f32x4){0.f, 0.f, 0.f, 0.f};
#pragma unroll
        for (int kst = 0; kst < 4; ++kst) {
            bf16x8 bfr = *(const bf16x8*)(wb + (t * 16 + mm) * 64 + kst * 16 + quad * 4);
            acc = __builtin_amdgcn_mfma_f32_16x16x32_bf16(bfr, afr[kst], acc, 0, 0, 0);
        }

        int node = n0 + s * 16 + mm;
        if (node < N_NODES) {
            int hb = t * 16 + quad * 4;
            float4 bb = *(const float4*)(bl + hb);
            ushort4 o;
            o.x = f2bf(fmaxf(acc[0] + bb.x, 0.f));
            o.y = f2bf(fmaxf(acc[1] + bb.y, 0.f));
            o.z = f2bf(fmaxf(acc[2] + bb.z, 0.f));
            o.w = f2bf(fmaxf(acc[3] + bb.w, 0.f));
            *(ushort4*)(xoutb + (long)node * HID + hb) = o;
        }
        __syncthreads();   // As reuse guard before next group's phase A
    }
}

// ---- one cooperative kernel: prep | fill | layer1 | layer2 | pool ----
__global__ __launch_bounds__(512, 4) void k_all(KParams p)
{
    cg::grid_group grid = cg::this_grid();
    __shared__ unsigned int elds[128 * EST];   // 18432 B
    __shared__ unsigned int As[NPB * AST];     //  8704 B
    __shared__ float part[8][8][8];            //  2048 B

    const int tid = threadIdx.x;
    const int bid = blockIdx.x;
    const int gsz = gridDim.x;
    const int nth = gsz * 512;

    // ---- phase 0: zero cnt/pstart/pend, pack W1/W2, pack embed -> per-block LDS ----
    for (int i = tid; i < EBUF_T; i += 512) {
        int t = i >> 5, c = i & 31;
        float2 v = ((const float2*)(p.embed + (long)t * HID))[c];
        elds[t * EST + c] = packbf(v.x, v.y);
    }
    for (int g0 = bid * 512 + tid; g0 < N_NODES + 2 * N_GRAPHS + 2 * PW_T; g0 += nth) {
        int g = g0;
        if (g < N_NODES) { p.cnt[g] = 0; continue; }
        g -= N_NODES;
        if (g < N_GRAPHS) { p.pstart[g] = 0; continue; }
        g -= N_GRAPHS;
        if (g < N_GRAPHS) { p.pend[g] = 0; continue; }
        g -= N_GRAPHS;
        {
            const float* Wl = (g < PW_T) ? p.W1l : p.W2l;
            const float* Wr = (g < PW_T) ? p.W1r : p.W2r;
            unsigned int* wb = (g < PW_T) ? p.wb1 : p.wb2;
            int i = (g < PW_T) ? g : g - PW_T;
            int h = i >> 6, c = i & 63;   // row h: uints 0..31 = Wl, 32..63 = Wr
            float2 v = (c < 32) ? ((const float2*)(Wl + (long)h * HID))[c]
                                : ((const float2*)(Wr + (long)h * HID))[c - 32];
            wb[i] = packbf(v.x, v.y);
        }
    }
    grid.sync();

    // ---- phase 1: edge bucket fill + batch boundaries ----
    for (int e = bid * 512 + tid; e < N_EDGES; e += nth) {
        int d = p.dst[e];
        int s = p.src[e];
        unsigned int t = (unsigned int)p.tok[s];   // L2-hot 200KB gather
        int pos = atomicAdd(&p.cnt[d], 1);
        if (pos < NB) p.bucket[(long)d * NB + pos] = (unsigned int)s | (t << 16);
    }
    for (int n = bid * 512 + tid; n < N_NODES; n += nth) {
        int b = p.batch[n];
        if (n == 0 || p.batch[n - 1] != b) p.pstart[b] = n;
        if (n == N_NODES - 1 || p.batch[n + 1] != b) p.pend[b] = n + 1;
    }
    grid.sync();

    // ---- phase 2: layer 1 (neighbors+self from LDS embed table via tok) ----
    layer_phase(true, p.cnt, p.bucket, p.tok, nullptr, p.wb1, p.b1l,
                (unsigned short*)p.x1b, As, elds, bid, gsz, tid);
    grid.sync();

    // ---- phase 3: layer 2 (neighbors+self from x1b) ----
    layer_phase(false, p.cnt, p.bucket, nullptr, p.x1b, p.wb2, p.b2l,
                (unsigned short*)p.x2b, As, elds, bid, gsz, tid);
    grid.sync();

    // ---- phase 4: pool + head (one graph per block-iteration, 8 waves) ----
    {
        const int wv   = tid >> 6;     // 0..7
        const int lane = tid & 63;
        const int q    = lane & 7;
        const int slot = wv * 8 + (lane >> 3);   // node slot 0..63
        for (int g = bid; g < N_GRAPHS; g += gsz) {
            int s = p.pstart[g], e = p.pend[g];
            float f0 = 0, f1 = 0, f2 = 0, f3 = 0, f4 = 0, f5 = 0, f6 = 0, f7 = 0;
            for (int n = s + slot; n < e; n += 64) {
                uint4 v = *((const uint4*)(p.x2b + (long)n * 32) + q);
                f0 += bf2f(v.x & 0xffff); f1 += bf2f(v.x >> 16);
                f2 += bf2f(v.y & 0xffff); f3 += bf2f(v.y >> 16);
                f4 += bf2f(v.z & 0xffff); f5 += bf2f(v.z >> 16);
                f6 += bf2f(v.w & 0xffff); f7 += bf2f(v.w >> 16);
            }
#pragma unroll
            for (int o = 8; o < 64; o <<= 1) {
                f0 += __shfl_xor(f0, o, 64); f1 += __shfl_xor(f1, o, 64);
                f2 += __shfl_xor(f2, o, 64); f3 += __shfl_xor(f3, o, 64);
                f4 += __shfl_xor(f4, o, 64); f5 += __shfl_xor(f5, o, 64);
                f6 += __shfl_xor(f6, o, 64); f7 += __shfl_xor(f7, o, 64);
            }
            if (lane < 8) {            // lane == q here
                part[wv][lane][0] = f0; part[wv][lane][1] = f1;
                part[wv][lane][2] = f2; part[wv][lane][3] = f3;
                part[wv][lane][4] = f4; part[wv][lane][5] = f5;
                part[wv][lane][6] = f6; part[wv][lane][7] = f7;
            }
            __syncthreads();
            if (wv == 0) {
                float s0 = 0, s1 = 0, s2 = 0, s3 = 0, s4 = 0, s5 = 0, s6 = 0, s7 = 0;
#pragma unroll
                for (int w = 0; w < 8; ++w) {
                    s0 += part[w][q][0]; s1 += part[w][q][1];
                    s2 += part[w][q][2]; s3 += part[w][q][3];
                    s4 += part[w][q][4]; s5 += part[w][q][5];
                    s6 += part[w][q][6]; s7 += part[w][q][7];
                }
                float inv = 1.0f / (float)max(e - s, 1);
                s0 *= inv; s1 *= inv; s2 *= inv; s3 *= inv;
                s4 *= inv; s5 *= inv; s6 *= inv; s7 *= inv;
#pragma unroll
                for (int c = 0; c < NCLS; ++c) {
                    const float* wr = p.Wlin + c * HID + q * 8;
                    float pr = s0 * wr[0] + s1 * wr[1] + s2 * wr[2] + s3 * wr[3] +
                               s4 * wr[4] + s5 * wr[5] + s6 * wr[6] + s7 * wr[7];
                    pr += __shfl_xor(pr, 1, 64);
                    pr += __shfl_xor(pr, 2, 64);
                    pr += __shfl_xor(pr, 4, 64);
                    if (lane == 0) p.out[g * NCLS + c] = pr + p.blin[c];
                }
            }
            __syncthreads();
        }
    }
}

// ================= fallback path: R3 kernels (used only if cooperative launch fails) =================
__global__ void k_prep_fill_fb(
    const int* __restrict__ src, const int* __restrict__ dst,
    const int* __restrict__ tok,
    int* __restrict__ cnt, unsigned int* __restrict__ bucket,
    const float* __restrict__ embed, unsigned int* __restrict__ ebufg,
    const int* __restrict__ batch,
    int* __restrict__ pos_start, int* __restrict__ pos_end,
    const float* __restrict__ W1l, const float* __restrict__ W1r,
    unsigned int* __restrict__ wb1,
    const float* __restrict__ W2l, const float* __restrict__ W2r,
    unsigned int* __restrict__ wb2) {
    int gid = blockIdx.x * blockDim.x + threadIdx.x;
    if (gid < N_EDGES) {
        int d = dst[gid];
        int s = src[gid];
        unsigned int t = (unsigned int)tok[s];
        int pos = atomicAdd(&cnt[d], 1);
        if (pos < NB) bucket[(long)d * NB + pos] = (unsigned int)s | (t << 16);
        return;
    }
    gid -= N_EDGES;
    if (gid < EBUF_T) {
        int t = gid >> 5, c = gid & 31;
        float2 v = ((const float2*)(embed + (long)t * HID))[c];
        ebufg[gid] = packbf(v.x, v.y);
        return;
    }
    gid -= EBUF_T;
    if (gid < N_NODES) {
        int n = gid;
        int b = batch[n];
        if (n == 0 || batch[n - 1] != b) pos_start[b] = n;
        if (n == N_NODES - 1 || batch[n + 1] != b) pos_end[b] = n + 1;
        return;
    }
    gid -= N_NODES;
    if (gid < 2 * PW_T) {
        const float* Wl = (gid < PW_T) ? W1l : W2l;
        const float* Wr = (gid < PW_T) ? W1r : W2r;
        unsigned int* wb = (gid < PW_T) ? wb1 : wb2;
        int i = (gid < PW_T) ? gid : gid - PW_T;
        int h = i >> 6, c = i & 63;
        float2 v = (c < 32) ? ((const float2*)(Wl + (long)h * HID))[c]
                            : ((const float2*)(Wr + (long)h * HID))[c - 32];
        wb[i] = packbf(v.x, v.y);
    }
}

template <bool L1>
__global__ __launch_bounds__(512) void k_layer_fb(
    const int* __restrict__ cnt, const unsigned int* __restrict__ bucket,
    const int* __restrict__ tok, const unsigned int* __restrict__ ebufg,
    const unsigned int* __restrict__ xb,
    const unsigned int* __restrict__ wb, const float* __restrict__ bl,
    unsigned short* __restrict__ xoutb)
{
    __shared__ unsigned int As[NPB * AST];
    __shared__ unsigned int elds[L1 ? 128 * EST : 1];
    const int tid  = threadIdx.x;
    const int bid  = blockIdx.x;

    if (L1) {
        for (int i = tid; i < EBUF_T; i += 512) {
            int t = i >> 5, c = i & 31;
            elds[t * EST + c] = ebufg[i];
        }
        __syncthreads();
    }
    layer_phase(L1, cnt, bucket, tok, xb, wb, bl, xoutb, As, elds, bid, 1 << 30, tid);
}

__global__ __launch_bounds__(256) void k_pool_fb(
    const unsigned int* __restrict__ x2b,
    const int* __restrict__ pos_start, const int* __restrict__ pos_end,
    const float* __restrict__ Wlin, const float* __restrict__ blin,
    float* __restrict__ out)
{
    __shared__ float part[4][8][8];
    int g    = blockIdx.x;
    int tid  = threadIdx.x;
    int wv   = tid >> 6;
    int lane = tid & 63;
    int q    = lane & 7;
    int slot = wv * 8 + (lane >> 3);
    int s = pos_start[g], e = pos_end[g];
    float f0 = 0, f1 = 0, f2 = 0, f3 = 0, f4 = 0, f5 = 0, f6 = 0, f7 = 0;
    for (int n = s + slot; n < e; n += 32) {
        uint4 v = *((const uint4*)(x2b + (long)n * 32) + q);
        f0 += bf2f(v.x & 0xffff); f1 += bf2f(v.x >> 16);
        f2 += bf2f(v.y & 0xffff); f3 += bf2f(v.y >> 16);
        f4 += bf2f(v.z & 0xffff); f5 += bf2f(v.z >> 16);
        f6 += bf2f(v.w & 0xffff); f7 += bf2f(v.w >> 16);
    }
#pragma unroll
    for (int o = 8; o < 64; o <<= 1) {
        f0 += __shfl_xor(f0, o, 64); f1 += __shfl_xor(f1, o, 64);
        f2 += __shfl_xor(f2, o, 64); f3 += __shfl_xor(f3, o, 64);
        f4 += __shfl_xor(f4, o, 64); f5 += __shfl_xor(f5, o, 64);
        f6 += __shfl_xor(f6, o, 64); f7 += __shfl_xor(f7, o, 64);
    }
    if (lane < 8) {
        part[wv][lane][0] = f0; part[wv][lane][1] = f1;
        part[wv][lane][2] = f2; part[wv][lane][3] = f3;
        part[wv][lane][4] = f4; part[wv][lane][5] = f5;
        part[wv][lane][6] = f6; part[wv][lane][7] = f7;
    }
    __syncthreads();
    if (wv == 0) {
        f0 = part[0][q][0] + part[1][q][0] + part[2][q][0] + part[3][q][0];
        f1 = part[0][q][1] + part[1][q][1] + part[2][q][1] + part[3][q][1];
        f2 = part[0][q][2] + part[1][q][2] + part[2][q][2] + part[3][q][2];
        f3 = part[0][q][3] + part[1][q][3] + part[2][q][3] + part[3][q][3];
        f4 = part[0][q][4] + part[1][q][4] + part[2][q][4] + part[3][q][4];
        f5 = part[0][q][5] + part[1][q][5] + part[2][q][5] + part[3][q][5];
        f6 = part[0][q][6] + part[1][q][6] + part[2][q][6] + part[3][q][6];
        f7 = part[0][q][7] + part[1][q][7] + part[2][q][7] + part[3][q][7];
        float inv = 1.0f / (float)max(e - s, 1);
        f0 *= inv; f1 *= inv; f2 *= inv; f3 *= inv;
        f4 *= inv; f5 *= inv; f6 *= inv; f7 *= inv;
#pragma unroll
        for (int c = 0; c < NCLS; ++c) {
            const float* wr = Wlin + c * HID + q * 8;
            float p = f0 * wr[0] + f1 * wr[1] + f2 * wr[2] + f3 * wr[3] +
                      f4 * wr[4] + f5 * wr[5] + f6 * wr[6] + f7 * wr[7];
            p += __shfl_xor(p, 1, 64);
            p += __shfl_xor(p, 2, 64);
            p += __shfl_xor(p, 4, 64);
            if (lane == 0) out[g * NCLS + c] = p + blin[c];
        }
    }
}

extern "C" void kernel_launch(void* const* d_in, const int* in_sizes, int n_in,
                              void* d_out, int out_size, void* d_ws, size_t ws_size,
                              hipStream_t stream) {
    const int*   tok   = (const int*)d_in[0];
    const int*   eidx  = (const int*)d_in[1];
    const int*   batch = (const int*)d_in[2];
    const float* embed = (const float*)d_in[3];
    const float* W1l   = (const float*)d_in[4];
    const float* b1l   = (const float*)d_in[5];
    const float* W1r   = (const float*)d_in[6];
    const float* W2l   = (const float*)d_in[7];
    const float* b2l   = (const float*)d_in[8];
    const float* W2r   = (const float*)d_in[9];
    const float* Wlin  = (const float*)d_in[10];
    const float* blin  = (const float*)d_in[11];
    float* out = (float*)d_out;

    const int* src = eidx;
    const int* dst = eidx + N_EDGES;

    char* wsp = (char*)d_ws;
    size_t off = 0;
    auto alloc = [&](size_t bytes) -> void* {
        void* p = wsp + off;
        off = (off + bytes + 255) & ~(size_t)255;
        return p;
    };
    int*   cnt     = (int*)  alloc((size_t)N_NODES * 4);
    int*   pstart  = (int*)  alloc((size_t)N_GRAPHS * 4);
    int*   pend    = (int*)  alloc((size_t)N_GRAPHS * 4);
    unsigned int* bucket = (unsigned int*)alloc((size_t)N_NODES * NB * 4);
    unsigned int* x1b    = (unsigned int*)alloc((size_t)N_NODES * 32 * 4);
    unsigned int* x2b    = (unsigned int*)alloc((size_t)N_NODES * 32 * 4);
    unsigned int* ebufg  = (unsigned int*)alloc((size_t)128 * 32 * 4);
    unsigned int* wb1    = (unsigned int*)alloc((size_t)64 * 64 * 4);
    unsigned int* wb2    = (unsigned int*)alloc((size_t)64 * 64 * 4);

    KParams kp;
    kp.src = src;   kp.dst = dst;   kp.tok = tok;   kp.batch = batch;
    kp.embed = embed;
    kp.W1l = W1l; kp.b1l = b1l; kp.W1r = W1r;
    kp.W2l = W2l; kp.b2l = b2l; kp.W2r = W2r;
    kp.Wlin = Wlin; kp.blin = blin;
    kp.cnt = cnt; kp.pstart = pstart; kp.pend = pend;
    kp.bucket = bucket; kp.x1b = x1b; kp.x2b = x2b;
    kp.wb1 = wb1; kp.wb2 = wb2; kp.out = out;

    static int bpc = 0;   // blocks per CU for k_all (queried once)
    if (bpc == 0) {
        if (hipOccupancyMaxActiveBlocksPerMultiprocessor(&bpc, k_all, 512, 0) != hipSuccess || bpc < 1)
            bpc = 2;      // __launch_bounds__(512,4) guarantees 2 blocks/CU
    }
    int grid = 256 * bpc;
    if (grid > 1024) grid = 1024;

    void* args[] = { (void*)&kp };
    hipError_t err = hipLaunchCooperativeKernel((void*)k_all, dim3(grid), dim3(512),
                                                args, 0, stream);
    if (err == hipSuccess) return;

    // -------- fallback: R3 multi-kernel path --------
    hipMemsetAsync(cnt, 0, (char*)pend - (char*)cnt + (size_t)N_GRAPHS * 4, stream);
    int prep_t = N_EDGES + EBUF_T + N_NODES + 2 * PW_T;
    k_prep_fill_fb<<<(prep_t + 255) / 256, 256, 0, stream>>>(
        src, dst, tok, cnt, bucket,
        embed, ebufg, batch, pstart, pend, W1l, W1r, wb1, W2l, W2r, wb2);
    k_layer_fb<true><<<NGRP, 512, 0, stream>>>(cnt, bucket, tok, ebufg, nullptr,
                                               wb1, b1l, (unsigned short*)x1b);
    k_layer_fb<false><<<NGRP, 512, 0, stream>>>(cnt, bucket, nullptr, nullptr, x1b,
                                                wb2, b2l, (unsigned short*)x2b);
    k_pool_fb<<<N_GRAPHS, 256, 0, stream>>>(x2b, pstart, pend, Wlin, blin, out);
}

// Round 5
// 393.258 us; speedup vs baseline: 1.0007x; 1.0007x over previous
//
#include <hip/hip_runtime.h>
#include <hip/hip_cooperative_groups.h>

namespace cg = cooperative_groups;

#define N_NODES  50000
#define N_EDGES  800000
#define N_GRAPHS 512
#define HID      64
#define NCLS     5
#define NB       64      // bucket capacity per node (max deg ~40 for this graph)
#define EST      36      // LDS embed row stride in uints
#define AST      68      // LDS As row stride in uints (64 data + 4 pad)
#define NPB      32      // nodes per block-iteration (R3 structure)
#define NGRP     ((N_NODES + NPB - 1) / NPB)   // 1563
#define EBUF_T   (128 * 32)
#define PW_T     (64 * 64)

typedef __attribute__((ext_vector_type(8))) short bf16x8;
typedef __attribute__((ext_vector_type(4))) float f32x4;

__device__ inline unsigned short f2bf(float f) {
    unsigned int u = __builtin_bit_cast(unsigned int, f);
    unsigned int r = (u + 0x7FFFu + ((u >> 16) & 1u)) >> 16;   // RNE
    return (unsigned short)r;
}
__device__ inline unsigned int packbf(float a, float b) {
    return (unsigned int)f2bf(a) | ((unsigned int)f2bf(b) << 16);
}
__device__ inline float bf2f(unsigned int u16) {
    unsigned int t = u16 << 16;
    return __builtin_bit_cast(float, t);
}

struct KParams {
    const int *src, *dst, *tok, *batch;
    const float *embed, *W1l, *b1l, *W1r, *W2l, *b2l, *W2r, *Wlin, *blin;
    int *cnt, *pstart, *pend, *gc;     // gc: 2 work-steal counters
    unsigned int *bucket, *x1b, *x2b, *wb1, *wb2;
    float *out;
};

// ---- one 32-node group of a SAGE layer (R3's proven k_layer body) ----
// Phase A: each wave gather-means 4 nodes from the bucket into bf16 LDS rows
// ([agg | x_self], K=128). Phase B: wave -> 16-node strip x 16-h tile, 4 MFMAs.
// Caller provides trailing __syncthreads before As is reused.
template <bool L1>
__device__ __forceinline__ void layer_group(
    int n0, const int* cnt, const unsigned int* bucket,
    const int* tok, const unsigned int* xb,
    const unsigned int* wb, const float* bl, unsigned short* xoutb,
    unsigned int* As, const unsigned int* elds, int tid)
{
    const int wv   = tid >> 6;        // 0..7
    const int lane = tid & 63;
    const int q    = lane & 7;        // 16B chunk (channels 8q..8q+7)
    const int e8   = lane >> 3;       // edge slot within group of 8

#pragma unroll
    for (int i = 0; i < 4; ++i) {
        int rl = wv * 4 + i;          // local row 0..31
        int nn = n0 + rl;
        int nc = min(nn, N_NODES - 1);
        int deg = cnt[nc];
        int m   = (nn < N_NODES) ? min(deg, NB) : 0;
        unsigned int v = (lane < m) ? bucket[(long)nc * NB + lane] : 0u;
        float f0 = 0, f1 = 0, f2 = 0, f3 = 0, f4 = 0, f5 = 0, f6 = 0, f7 = 0;
#pragma unroll
        for (int g = 0; g < 8; ++g) {
            int j = g * 8 + e8;
            unsigned int vv = __shfl(v, j, 64);
            if (j < m) {
                uint4 w4;
                if (L1) w4 = *(const uint4*)(elds + (vv >> 16) * EST + q * 4);
                else    w4 = *((const uint4*)(xb + (long)(vv & 0xffffu) * 32) + q);
                f0 += bf2f(w4.x & 0xffff); f1 += bf2f(w4.x >> 16);
                f2 += bf2f(w4.y & 0xffff); f3 += bf2f(w4.y >> 16);
                f4 += bf2f(w4.z & 0xffff); f5 += bf2f(w4.z >> 16);
                f6 += bf2f(w4.w & 0xffff); f7 += bf2f(w4.w >> 16);
            }
        }
#pragma unroll
        for (int o = 8; o < 64; o <<= 1) {
            f0 += __shfl_xor(f0, o, 64); f1 += __shfl_xor(f1, o, 64);
            f2 += __shfl_xor(f2, o, 64); f3 += __shfl_xor(f3, o, 64);
            f4 += __shfl_xor(f4, o, 64); f5 += __shfl_xor(f5, o, 64);
            f6 += __shfl_xor(f6, o, 64); f7 += __shfl_xor(f7, o, 64);
        }
        if (e8 == 0) {
            float inv = 1.0f / (float)max(deg, 1);
            uint4 o;
            o.x = packbf(f0 * inv, f1 * inv);
            o.y = packbf(f2 * inv, f3 * inv);
            o.z = packbf(f4 * inv, f5 * inv);
            o.w = packbf(f6 * inv, f7 * inv);
            *(uint4*)(As + rl * AST + q * 4) = o;
        } else if (e8 == 1) {
            uint4 sv;
            if (L1) { int tk = tok[nc]; sv = *(const uint4*)(elds + tk * EST + q * 4); }
            else    { sv = *((const uint4*)(xb + (long)nc * 32) + q); }
            *(uint4*)(As + rl * AST + 32 + q * 4) = sv;
        }
    }
    __syncthreads();

    // Phase B: wave wv -> strip s = wv&1 (16 nodes), h-tile t = wv>>1
    const int s    = wv & 1;
    const int t    = wv >> 1;
    const int mm   = lane & 15;
    const int quad = lane >> 4;

    bf16x8 afr[4];
#pragma unroll
    for (int kst = 0; kst < 4; ++kst)
        afr[kst] = *(const bf16x8*)(As + (s * 16 + mm) * AST + kst * 16 + quad * 4);

    f32x4 acc = (f32x4){0.f, 0.f, 0.f, 0.f};
#pragma unroll
    for (int kst = 0; kst < 4; ++kst) {
        bf16x8 bfr = *(const bf16x8*)(wb + (t * 16 + mm) * 64 + kst * 16 + quad * 4);
        acc = __builtin_amdgcn_mfma_f32_16x16x32_bf16(bfr, afr[kst], acc, 0, 0, 0);
    }

    int node = n0 + s * 16 + mm;
    if (node < N_NODES) {
        int hb = t * 16 + quad * 4;
        float4 bb = *(const float4*)(bl + hb);
        ushort4 o;
        o.x = f2bf(fmaxf(acc[0] + bb.x, 0.f));
        o.y = f2bf(fmaxf(acc[1] + bb.y, 0.f));
        o.z = f2bf(fmaxf(acc[2] + bb.z, 0.f));
        o.w = f2bf(fmaxf(acc[3] + bb.w, 0.f));
        *(ushort4*)(xoutb + (long)node * HID + hb) = o;
    }
}

// ---- one cooperative kernel: prep | fill | layer1 | layer2 | pool ----
// NOTE: plain __launch_bounds__(512) — NO waves-per-eu arg. R4's (512,4) set
// amdgpu-waves-per-eu=4 and the scheduler strangled the kernel to 36 VGPRs,
// serializing the gather pipeline (483us, VALUBusy 5%). Registers must float.
__global__ __launch_bounds__(512) void k_all(KParams p)
{
    cg::grid_group grid = cg::this_grid();
    __shared__ unsigned int elds[128 * EST];   // 18432 B
    __shared__ unsigned int As[NPB * AST];     //  8704 B (overlaid as pool 'part')
    __shared__ int s_grp;

    const int tid = threadIdx.x;
    const int bid = blockIdx.x;
    const int gsz = gridDim.x;
    const int nth = gsz * 512;

    // ---- phase 0: steal-counters, zero cnt/pstart/pend, pack W1/W2, embed->LDS ----
    if (bid == 0 && tid < 2) p.gc[tid] = 0;
    for (int i = tid; i < EBUF_T; i += 512) {
        int t = i >> 5, c = i & 31;
        float2 v = ((const float2*)(p.embed + (long)t * HID))[c];
        elds[t * EST + c] = packbf(v.x, v.y);
    }
    for (int g0 = bid * 512 + tid; g0 < N_NODES + 2 * N_GRAPHS + 2 * PW_T; g0 += nth) {
        int g = g0;
        if (g < N_NODES) { p.cnt[g] = 0; continue; }
        g -= N_NODES;
        if (g < N_GRAPHS) { p.pstart[g] = 0; continue; }
        g -= N_GRAPHS;
        if (g < N_GRAPHS) { p.pend[g] = 0; continue; }
        g -= N_GRAPHS;
        {
            const float* Wl = (g < PW_T) ? p.W1l : p.W2l;
            const float* Wr = (g < PW_T) ? p.W1r : p.W2r;
            unsigned int* wb = (g < PW_T) ? p.wb1 : p.wb2;
            int i = (g < PW_T) ? g : g - PW_T;
            int h = i >> 6, c = i & 63;   // row h: uints 0..31 = Wl, 32..63 = Wr
            float2 v = (c < 32) ? ((const float2*)(Wl + (long)h * HID))[c]
                                : ((const float2*)(Wr + (long)h * HID))[c - 32];
            wb[i] = packbf(v.x, v.y);
        }
    }
    grid.sync();

    // ---- phase 1: edge bucket fill + batch boundaries ----
    for (int e = bid * 512 + tid; e < N_EDGES; e += nth) {
        int d = p.dst[e];
        int s = p.src[e];
        unsigned int t = (unsigned int)p.tok[s];   // L2-hot 200KB gather
        int pos = atomicAdd(&p.cnt[d], 1);
        if (pos < NB) p.bucket[(long)d * NB + pos] = (unsigned int)s | (t << 16);
    }
    for (int n = bid * 512 + tid; n < N_NODES; n += nth) {
        int b = p.batch[n];
        if (n == 0 || p.batch[n - 1] != b) p.pstart[b] = n;
        if (n == N_NODES - 1 || p.batch[n + 1] != b) p.pend[b] = n + 1;
    }
    grid.sync();

    // ---- phase 2: layer 1 (work-stealing over node groups) ----
    while (true) {
        if (tid == 0) s_grp = atomicAdd(&p.gc[0], 1);
        __syncthreads();
        int grp = s_grp;
        if (grp >= NGRP) break;
        layer_group<true>(grp * NPB, p.cnt, p.bucket, p.tok, nullptr,
                          p.wb1, p.b1l, (unsigned short*)p.x1b, As, elds, tid);
        __syncthreads();   // As + s_grp reuse guard
    }
    grid.sync();

    // ---- phase 3: layer 2 ----
    while (true) {
        if (tid == 0) s_grp = atomicAdd(&p.gc[1], 1);
        __syncthreads();
        int grp = s_grp;
        if (grp >= NGRP) break;
        layer_group<false>(grp * NPB, p.cnt, p.bucket, nullptr, p.x1b,
                           p.wb2, p.b2l, (unsigned short*)p.x2b, As, elds, tid);
        __syncthreads();
    }
    grid.sync();

    // ---- phase 4: pool + head (one graph per block-iteration, 8 waves) ----
    {
        float* part = (float*)As;      // [8][8][8] overlay, 2048 B
        const int wv   = tid >> 6;     // 0..7
        const int lane = tid & 63;
        const int q    = lane & 7;
        const int slot = wv * 8 + (lane >> 3);   // node slot 0..63
        for (int g = bid; g < N_GRAPHS; g += gsz) {
            int s = p.pstart[g], e = p.pend[g];
            float f0 = 0, f1 = 0, f2 = 0, f3 = 0, f4 = 0, f5 = 0, f6 = 0, f7 = 0;
            for (int n = s + slot; n < e; n += 64) {
                uint4 v = *((const uint4*)(p.x2b + (long)n * 32) + q);
                f0 += bf2f(v.x & 0xffff); f1 += bf2f(v.x >> 16);
                f2 += bf2f(v.y & 0xffff); f3 += bf2f(v.y >> 16);
                f4 += bf2f(v.z & 0xffff); f5 += bf2f(v.z >> 16);
                f6 += bf2f(v.w & 0xffff); f7 += bf2f(v.w >> 16);
            }
#pragma unroll
            for (int o = 8; o < 64; o <<= 1) {
                f0 += __shfl_xor(f0, o, 64); f1 += __shfl_xor(f1, o, 64);
                f2 += __shfl_xor(f2, o, 64); f3 += __shfl_xor(f3, o, 64);
                f4 += __shfl_xor(f4, o, 64); f5 += __shfl_xor(f5, o, 64);
                f6 += __shfl_xor(f6, o, 64); f7 += __shfl_xor(f7, o, 64);
            }
            if (lane < 8) {            // lane == q here
                float* pp = part + (wv * 8 + lane) * 8;
                pp[0] = f0; pp[1] = f1; pp[2] = f2; pp[3] = f3;
                pp[4] = f4; pp[5] = f5; pp[6] = f6; pp[7] = f7;
            }
            __syncthreads();
            if (wv == 0) {
                float s0 = 0, s1 = 0, s2 = 0, s3 = 0, s4 = 0, s5 = 0, s6 = 0, s7 = 0;
#pragma unroll
                for (int w = 0; w < 8; ++w) {
                    const float* pp = part + (w * 8 + q) * 8;
                    s0 += pp[0]; s1 += pp[1]; s2 += pp[2]; s3 += pp[3];
                    s4 += pp[4]; s5 += pp[5]; s6 += pp[6]; s7 += pp[7];
                }
                float inv = 1.0f / (float)max(e - s, 1);
                s0 *= inv; s1 *= inv; s2 *= inv; s3 *= inv;
                s4 *= inv; s5 *= inv; s6 *= inv; s7 *= inv;
#pragma unroll
                for (int c = 0; c < NCLS; ++c) {
                    const float* wr = p.Wlin + c * HID + q * 8;
                    float pr = s0 * wr[0] + s1 * wr[1] + s2 * wr[2] + s3 * wr[3] +
                               s4 * wr[4] + s5 * wr[5] + s6 * wr[6] + s7 * wr[7];
                    pr += __shfl_xor(pr, 1, 64);
                    pr += __shfl_xor(pr, 2, 64);
                    pr += __shfl_xor(pr, 4, 64);
                    if (lane == 0) p.out[g * NCLS + c] = pr + p.blin[c];
                }
            }
            __syncthreads();
        }
    }
}

// ================= fallback path: R3 kernels (used only if cooperative launch fails) =================
__global__ void k_prep_fill_fb(
    const int* __restrict__ src, const int* __restrict__ dst,
    const int* __restrict__ tok,
    int* __restrict__ cnt, unsigned int* __restrict__ bucket,
    const float* __restrict__ embed, unsigned int* __restrict__ ebufg,
    const int* __restrict__ batch,
    int* __restrict__ pos_start, int* __restrict__ pos_end,
    const float* __restrict__ W1l, const float* __restrict__ W1r,
    unsigned int* __restrict__ wb1,
    const float* __restrict__ W2l, const float* __restrict__ W2r,
    unsigned int* __restrict__ wb2) {
    int gid = blockIdx.x * blockDim.x + threadIdx.x;
    if (gid < N_EDGES) {
        int d = dst[gid];
        int s = src[gid];
        unsigned int t = (unsigned int)tok[s];
        int pos = atomicAdd(&cnt[d], 1);
        if (pos < NB) bucket[(long)d * NB + pos] = (unsigned int)s | (t << 16);
        return;
    }
    gid -= N_EDGES;
    if (gid < EBUF_T) {
        int t = gid >> 5, c = gid & 31;
        float2 v = ((const float2*)(embed + (long)t * HID))[c];
        ebufg[gid] = packbf(v.x, v.y);
        return;
    }
    gid -= EBUF_T;
    if (gid < N_NODES) {
        int n = gid;
        int b = batch[n];
        if (n == 0 || batch[n - 1] != b) pos_start[b] = n;
        if (n == N_NODES - 1 || batch[n + 1] != b) pos_end[b] = n + 1;
        return;
    }
    gid -= N_NODES;
    if (gid < 2 * PW_T) {
        const float* Wl = (gid < PW_T) ? W1l : W2l;
        const float* Wr = (gid < PW_T) ? W1r : W2r;
        unsigned int* wb = (gid < PW_T) ? wb1 : wb2;
        int i = (gid < PW_T) ? gid : gid - PW_T;
        int h = i >> 6, c = i & 63;
        float2 v = (c < 32) ? ((const float2*)(Wl + (long)h * HID))[c]
                            : ((const float2*)(Wr + (long)h * HID))[c - 32];
        wb[i] = packbf(v.x, v.y);
    }
}

template <bool L1>
__global__ __launch_bounds__(512) void k_layer_fb(
    const int* __restrict__ cnt, const unsigned int* __restrict__ bucket,
    const int* __restrict__ tok, const unsigned int* __restrict__ ebufg,
    const unsigned int* __restrict__ xb,
    const unsigned int* __restrict__ wb, const float* __restrict__ bl,
    unsigned short* __restrict__ xoutb)
{
    __shared__ unsigned int As[NPB * AST];
    __shared__ unsigned int elds[L1 ? 128 * EST : 1];
    const int tid = threadIdx.x;

    if (L1) {
        for (int i = tid; i < EBUF_T; i += 512) {
            int t = i >> 5, c = i & 31;
            elds[t * EST + c] = ebufg[i];
        }
        __syncthreads();
    }
    layer_group<L1>(blockIdx.x * NPB, cnt, bucket, tok, xb, wb, bl, xoutb, As, elds, tid);
}

__global__ __launch_bounds__(256) void k_pool_fb(
    const unsigned int* __restrict__ x2b,
    const int* __restrict__ pos_start, const int* __restrict__ pos_end,
    const float* __restrict__ Wlin, const float* __restrict__ blin,
    float* __restrict__ out)
{
    __shared__ float part[4][8][8];
    int g    = blockIdx.x;
    int tid  = threadIdx.x;
    int wv   = tid >> 6;
    int lane = tid & 63;
    int q    = lane & 7;
    int slot = wv * 8 + (lane >> 3);
    int s = pos_start[g], e = pos_end[g];
    float f0 = 0, f1 = 0, f2 = 0, f3 = 0, f4 = 0, f5 = 0, f6 = 0, f7 = 0;
    for (int n = s + slot; n < e; n += 32) {
        uint4 v = *((const uint4*)(x2b + (long)n * 32) + q);
        f0 += bf2f(v.x & 0xffff); f1 += bf2f(v.x >> 16);
        f2 += bf2f(v.y & 0xffff); f3 += bf2f(v.y >> 16);
        f4 += bf2f(v.z & 0xffff); f5 += bf2f(v.z >> 16);
        f6 += bf2f(v.w & 0xffff); f7 += bf2f(v.w >> 16);
    }
#pragma unroll
    for (int o = 8; o < 64; o <<= 1) {
        f0 += __shfl_xor(f0, o, 64); f1 += __shfl_xor(f1, o, 64);
        f2 += __shfl_xor(f2, o, 64); f3 += __shfl_xor(f3, o, 64);
        f4 += __shfl_xor(f4, o, 64); f5 += __shfl_xor(f5, o, 64);
        f6 += __shfl_xor(f6, o, 64); f7 += __shfl_xor(f7, o, 64);
    }
    if (lane < 8) {
        part[wv][lane][0] = f0; part[wv][lane][1] = f1;
        part[wv][lane][2] = f2; part[wv][lane][3] = f3;
        part[wv][lane][4] = f4; part[wv][lane][5] = f5;
        part[wv][lane][6] = f6; part[wv][lane][7] = f7;
    }
    __syncthreads();
    if (wv == 0) {
        f0 = part[0][q][0] + part[1][q][0] + part[2][q][0] + part[3][q][0];
        f1 = part[0][q][1] + part[1][q][1] + part[2][q][1] + part[3][q][1];
        f2 = part[0][q][2] + part[1][q][2] + part[2][q][2] + part[3][q][2];
        f3 = part[0][q][3] + part[1][q][3] + part[2][q][3] + part[3][q][3];
        f4 = part[0][q][4] + part[1][q][4] + part[2][q][4] + part[3][q][4];
        f5 = part[0][q][5] + part[1][q][5] + part[2][q][5] + part[3][q][5];
        f6 = part[0][q][6] + part[1][q][6] + part[2][q][6] + part[3][q][6];
        f7 = part[0][q][7] + part[1][q][7] + part[2][q][7] + part[3][q][7];
        float inv = 1.0f / (float)max(e - s, 1);
        f0 *= inv; f1 *= inv; f2 *= inv; f3 *= inv;
        f4 *= inv; f5 *= inv; f6 *= inv; f7 *= inv;
#pragma unroll
        for (int c = 0; c < NCLS; ++c) {
            const float* wr = Wlin + c * HID + q * 8;
            float p = f0 * wr[0] + f1 * wr[1] + f2 * wr[2] + f3 * wr[3] +
                      f4 * wr[4] + f5 * wr[5] + f6 * wr[6] + f7 * wr[7];
            p += __shfl_xor(p, 1, 64);
            p += __shfl_xor(p, 2, 64);
            p += __shfl_xor(p, 4, 64);
            if (lane == 0) out[g * NCLS + c] = p + blin[c];
        }
    }
}

extern "C" void kernel_launch(void* const* d_in, const int* in_sizes, int n_in,
                              void* d_out, int out_size, void* d_ws, size_t ws_size,
                              hipStream_t stream) {
    const int*   tok   = (const int*)d_in[0];
    const int*   eidx  = (const int*)d_in[1];
    const int*   batch = (const int*)d_in[2];
    const float* embed = (const float*)d_in[3];
    const float* W1l   = (const float*)d_in[4];
    const float* b1l   = (const float*)d_in[5];
    const float* W1r   = (const float*)d_in[6];
    const float* W2l   = (const float*)d_in[7];
    const float* b2l   = (const float*)d_in[8];
    const float* W2r   = (const float*)d_in[9];
    const float* Wlin  = (const float*)d_in[10];
    const float* blin  = (const float*)d_in[11];
    float* out = (float*)d_out;

    const int* src = eidx;
    const int* dst = eidx + N_EDGES;

    char* wsp = (char*)d_ws;
    size_t off = 0;
    auto alloc = [&](size_t bytes) -> void* {
        void* p = wsp + off;
        off = (off + bytes + 255) & ~(size_t)255;
        return p;
    };
    int*   cnt     = (int*)  alloc((size_t)N_NODES * 4);
    int*   pstart  = (int*)  alloc((size_t)N_GRAPHS * 4);
    int*   pend    = (int*)  alloc((size_t)N_GRAPHS * 4);
    int*   gc      = (int*)  alloc(2 * 4);
    unsigned int* bucket = (unsigned int*)alloc((size_t)N_NODES * NB * 4);
    unsigned int* x1b    = (unsigned int*)alloc((size_t)N_NODES * 32 * 4);
    unsigned int* x2b    = (unsigned int*)alloc((size_t)N_NODES * 32 * 4);
    unsigned int* ebufg  = (unsigned int*)alloc((size_t)128 * 32 * 4);
    unsigned int* wb1    = (unsigned int*)alloc((size_t)64 * 64 * 4);
    unsigned int* wb2    = (unsigned int*)alloc((size_t)64 * 64 * 4);

    KParams kp;
    kp.src = src;   kp.dst = dst;   kp.tok = tok;   kp.batch = batch;
    kp.embed = embed;
    kp.W1l = W1l; kp.b1l = b1l; kp.W1r = W1r;
    kp.W2l = W2l; kp.b2l = b2l; kp.W2r = W2r;
    kp.Wlin = Wlin; kp.blin = blin;
    kp.cnt = cnt; kp.pstart = pstart; kp.pend = pend; kp.gc = gc;
    kp.bucket = bucket; kp.x1b = x1b; kp.x2b = x2b;
    kp.wb1 = wb1; kp.wb2 = wb2; kp.out = out;

    static int bpc = 0;   // blocks per CU for k_all (queried once)
    if (bpc == 0) {
        if (hipOccupancyMaxActiveBlocksPerMultiprocessor(&bpc, k_all, 512, 0) != hipSuccess || bpc < 1)
            bpc = 1;      // 1 block/CU always co-resident (8 waves, 28KB LDS)
        if (bpc > 4) bpc = 4;   // waves cap: 32/8
    }
    int grid = 256 * bpc;

    void* args[] = { (void*)&kp };
    hipError_t err = hipLaunchCooperativeKernel((void*)k_all, dim3(grid), dim3(512),
                                                args, 0, stream);
    if (err == hipSuccess) return;

    // -------- fallback: R3 multi-kernel path --------
    hipMemsetAsync(cnt, 0, (char*)pend - (char*)cnt + (size_t)N_GRAPHS * 4, stream);
    int prep_t = N_EDGES + EBUF_T + N_NODES + 2 * PW_T;
    k_prep_fill_fb<<<(prep_t + 255) / 256, 256, 0, stream>>>(
        src, dst, tok, cnt, bucket,
        embed, ebufg, batch, pstart, pend, W1l, W1r, wb1, W2l, W2r, wb2);
    k_layer_fb<true><<<NGRP, 512, 0, stream>>>(cnt, bucket, tok, ebufg, nullptr,
                                               wb1, b1l, (unsigned short*)x1b);
    k_layer_fb<false><<<NGRP, 512, 0, stream>>>(cnt, bucket, nullptr, nullptr, x1b,
                                                wb2, b2l, (unsigned short*)x2b);
    k_pool_fb<<<N_GRAPHS, 256, 0, stream>>>(x2b, pstart, pend, Wlin, blin, out);
}

// Round 6
// 188.059 us; speedup vs baseline: 2.0926x; 2.0911x over previous
//
#include <hip/hip_runtime.h>

#define N_NODES  50000
#define N_EDGES  800000
#define N_GRAPHS 512
#define HID      64
#define NCLS     5
#define NB       64      // bucket capacity per node (max deg ~40 for this graph)
#define EST      36      // LDS embed row stride in uints
#define AST      68      // LDS As row stride in uints (64 data + 4 pad)

typedef __attribute__((ext_vector_type(8))) short bf16x8;
typedef __attribute__((ext_vector_type(4))) float f32x4;

__device__ inline unsigned short f2bf(float f) {
    unsigned int u = __builtin_bit_cast(unsigned int, f);
    unsigned int r = (u + 0x7FFFu + ((u >> 16) & 1u)) >> 16;   // RNE
    return (unsigned short)r;
}
__device__ inline unsigned int packbf(float a, float b) {
    return (unsigned int)f2bf(a) | ((unsigned int)f2bf(b) << 16);
}
__device__ inline float bf2f(unsigned int u16) {
    unsigned int t = u16 << 16;
    return __builtin_bit_cast(float, t);
}

// ------- merged prep+fill (R1/R3 form + 2-edge ILP) -------
// Edge section 8x replicated with static XCD-range filter: block b handles edge
// chunk b/8 (512 edges, 2 per thread), dst range (b%8)*6250..+6250.
// Mapping-independent-correct: every (chunk, range) pair processed exactly once.
// 2 edges/thread -> two independent dst->tok->atomic->store chains per thread
// (2-way memory-level parallelism in a latency-chain-bound section).
#define XCDS   8
#define NPX    (N_NODES / XCDS)                     // 6250, exact
#define EPB    512                                  // edges per chunk
#define ECH2   ((N_EDGES + EPB - 1) / EPB)          // 1563 chunks
#define SEC_E  (ECH2 * XCDS * 256)                  // 3,201,024 threads
#define EBUF_T (128 * 32)
#define PW_T   (64 * 64)
#define PREP_T (SEC_E + EBUF_T + N_NODES + 2 * PW_T)
__global__ void k_prep_fill(
    const int* __restrict__ src, const int* __restrict__ dst,
    const int* __restrict__ tok,
    int* __restrict__ cnt, unsigned int* __restrict__ bucket,
    const float* __restrict__ embed, unsigned int* __restrict__ ebufg,
    const int* __restrict__ batch,
    int* __restrict__ pos_start, int* __restrict__ pos_end,
    const float* __restrict__ W1l, const float* __restrict__ W1r,
    unsigned int* __restrict__ wb1,
    const float* __restrict__ W2l, const float* __restrict__ W2r,
    unsigned int* __restrict__ wb2) {
    int gid = blockIdx.x * blockDim.x + threadIdx.x;
    if (gid < SEC_E) {
        int blk   = gid >> 8;          // == blockIdx.x within this section
        int tidl  = gid & 255;
        int range = blk & 7;           // XCD slot (round-robin heuristic)
        int chunk = blk >> 3;          // 0..1562
        int lo = range * NPX;
        int e0 = chunk * EPB + tidl;
        int e1 = e0 + 256;
        int d0 = (e0 < N_EDGES) ? dst[e0] : -1;
        int d1 = (e1 < N_EDGES) ? dst[e1] : -1;
        int s0 = (e0 < N_EDGES) ? src[e0] : 0;
        int s1 = (e1 < N_EDGES) ? src[e1] : 0;
        bool k0 = (d0 >= lo) && (d0 < lo + NPX);
        bool k1 = (d1 >= lo) && (d1 < lo + NPX);
        unsigned int t0 = k0 ? (unsigned int)tok[s0] : 0u;   // L2-hot 200KB gather
        unsigned int t1 = k1 ? (unsigned int)tok[s1] : 0u;
        if (k0) {
            int pos = atomicAdd(&cnt[d0], 1);
            if (pos < NB) bucket[(long)d0 * NB + pos] = (unsigned int)s0 | (t0 << 16);
        }
        if (k1) {
            int pos = atomicAdd(&cnt[d1], 1);
            if (pos < NB) bucket[(long)d1 * NB + pos] = (unsigned int)s1 | (t1 << 16);
        }
        return;
    }
    gid -= SEC_E;
    if (gid < EBUF_T) {
        int t = gid >> 5, c = gid & 31;
        float2 v = ((const float2*)(embed + (long)t * HID))[c];
        ebufg[gid] = packbf(v.x, v.y);
        return;
    }
    gid -= EBUF_T;
    if (gid < N_NODES) {
        int n = gid;
        int b = batch[n];
        if (n == 0 || batch[n - 1] != b) pos_start[b] = n;
        if (n == N_NODES - 1 || batch[n + 1] != b) pos_end[b] = n + 1;
        return;
    }
    gid -= N_NODES;
    if (gid < 2 * PW_T) {
        const float* Wl = (gid < PW_T) ? W1l : W2l;
        const float* Wr = (gid < PW_T) ? W1r : W2r;
        unsigned int* wb = (gid < PW_T) ? wb1 : wb2;
        int i = (gid < PW_T) ? gid : gid - PW_T;
        int h = i >> 6, c = i & 63;   // row h: uints 0..31 = Wl, 32..63 = Wr
        float2 v = (c < 32) ? ((const float2*)(Wl + (long)h * HID))[c]
                            : ((const float2*)(Wr + (long)h * HID))[c - 32];
        wb[i] = packbf(v.x, v.y);
    }
}

// ------- fused layer, templated on nodes-per-block ----
// NPBT=32 (512 thr, 8 waves) for layer 1: elds staging (16KB) amortized over
// 32 nodes; gathers come from LDS (low latency, TLP less critical).
// NPBT=16 (256 thr, 4 waves) for layer 2: gathers are random 128B x1b rows
// from L2/L3 (~300-900cy) -> more, smaller blocks per CU = more independent
// latency chains + finer barrier granularity.
// Phase A: wave aggregates 4 nodes (gather-mean from bucket) into bf16 LDS
// rows ([agg | x_self], K=128). Phase B: wave -> 16-node strip x 16-h tile,
// 4 MFMAs (C^T), one ushort4 full-line store per lane.
template <bool L1, int NPBT>
__global__ __launch_bounds__(NPBT * 16) void k_layer(
    const int* __restrict__ cnt, const unsigned int* __restrict__ bucket,
    const int* __restrict__ tok, const unsigned int* __restrict__ ebufg,
    const unsigned int* __restrict__ xb,
    const unsigned int* __restrict__ wb, const float* __restrict__ bl,
    unsigned short* __restrict__ xoutb)
{
    __shared__ unsigned int As[NPBT * AST];
    __shared__ unsigned int elds[L1 ? 128 * EST : 1];
    const int tid  = threadIdx.x;
    const int wv   = tid >> 6;        // 0..NPBT/4-1
    const int lane = tid & 63;
    const int n0   = blockIdx.x * NPBT;

    if (L1) {
        for (int i = tid; i < EBUF_T; i += NPBT * 16) {
            int t = i >> 5, c = i & 31;
            elds[t * EST + c] = ebufg[i];
        }
        __syncthreads();
    }

    const int q  = lane & 7;          // 16B chunk (channels 8q..8q+7)
    const int e8 = lane >> 3;         // edge slot within group of 8

#pragma unroll
    for (int i = 0; i < 4; ++i) {
        int rl = wv * 4 + i;          // local row 0..NPBT-1
        int nn = n0 + rl;
        int nc = min(nn, N_NODES - 1);
        int deg = cnt[nc];
        int m   = (nn < N_NODES) ? min(deg, NB) : 0;
        unsigned int v = (lane < m) ? bucket[(long)nc * NB + lane] : 0u;
        float f0 = 0, f1 = 0, f2 = 0, f3 = 0, f4 = 0, f5 = 0, f6 = 0, f7 = 0;
#pragma unroll
        for (int g = 0; g < 8; ++g) {
            int j = g * 8 + e8;
            unsigned int vv = __shfl(v, j, 64);
            if (j < m) {
                uint4 w4;
                if (L1) w4 = *(const uint4*)(elds + (vv >> 16) * EST + q * 4);
                else    w4 = *((const uint4*)(xb + (long)(vv & 0xffffu) * 32) + q);
                f0 += bf2f(w4.x & 0xffff); f1 += bf2f(w4.x >> 16);
                f2 += bf2f(w4.y & 0xffff); f3 += bf2f(w4.y >> 16);
                f4 += bf2f(w4.z & 0xffff); f5 += bf2f(w4.z >> 16);
                f6 += bf2f(w4.w & 0xffff); f7 += bf2f(w4.w >> 16);
            }
        }
#pragma unroll
        for (int o = 8; o < 64; o <<= 1) {
            f0 += __shfl_xor(f0, o, 64); f1 += __shfl_xor(f1, o, 64);
            f2 += __shfl_xor(f2, o, 64); f3 += __shfl_xor(f3, o, 64);
            f4 += __shfl_xor(f4, o, 64); f5 += __shfl_xor(f5, o, 64);
            f6 += __shfl_xor(f6, o, 64); f7 += __shfl_xor(f7, o, 64);
        }
        if (e8 == 0) {
            float inv = 1.0f / (float)max(deg, 1);
            uint4 o;
            o.x = packbf(f0 * inv, f1 * inv);
            o.y = packbf(f2 * inv, f3 * inv);
            o.z = packbf(f4 * inv, f5 * inv);
            o.w = packbf(f6 * inv, f7 * inv);
            *(uint4*)(As + rl * AST + q * 4) = o;
        } else if (e8 == 1) {
            uint4 sv;
            if (L1) { int tk = tok[nc]; sv = *(const uint4*)(elds + tk * EST + q * 4); }
            else    { sv = *((const uint4*)(xb + (long)nc * 32) + q); }
            *(uint4*)(As + rl * AST + 32 + q * 4) = sv;
        }
    }
    __syncthreads();

    // Phase B: wave wv -> strip s (16 nodes), h-tile t (16 channels)
    constexpr int NSTR = NPBT / 16;   // strips per block (2 or 1)
    const int s    = wv % NSTR;
    const int t    = wv / NSTR;
    const int mm   = lane & 15;
    const int quad = lane >> 4;

    bf16x8 afr[4];
#pragma unroll
    for (int kst = 0; kst < 4; ++kst)
        afr[kst] = *(const bf16x8*)(As + (s * 16 + mm) * AST + kst * 16 + quad * 4);

    f32x4 acc = (f32x4){0.f, 0.f, 0.f, 0.f};
#pragma unroll
    for (int kst = 0; kst < 4; ++kst) {
        bf16x8 bfr = *(const bf16x8*)(wb + (t * 16 + mm) * 64 + kst * 16 + quad * 4);
        acc = __builtin_amdgcn_mfma_f32_16x16x32_bf16(bfr, afr[kst], acc, 0, 0, 0);
    }

    // C^T[h][node]: h = t*16 + quad*4 + r, node = n0 + s*16 + mm
    int node = n0 + s * 16 + mm;
    if (node < N_NODES) {
        int hb = t * 16 + quad * 4;
        float4 bb = *(const float4*)(bl + hb);
        ushort4 o;
        o.x = f2bf(fmaxf(acc[0] + bb.x, 0.f));
        o.y = f2bf(fmaxf(acc[1] + bb.y, 0.f));
        o.z = f2bf(fmaxf(acc[2] + bb.z, 0.f));
        o.w = f2bf(fmaxf(acc[3] + bb.w, 0.f));
        *(ushort4*)(xoutb + (long)node * HID + hb) = o;
    }
}

// ------- pool + head: 4 waves per graph; batch sorted -> contiguous range -------
__global__ __launch_bounds__(256) void k_pool(
    const unsigned int* __restrict__ x2b,
    const int* __restrict__ pos_start, const int* __restrict__ pos_end,
    const float* __restrict__ Wlin, const float* __restrict__ blin,
    float* __restrict__ out)
{
    __shared__ float part[4][8][8];   // [wave][q][channel j]
    int g    = blockIdx.x;
    int tid  = threadIdx.x;
    int wv   = tid >> 6;     // 0..3
    int lane = tid & 63;
    int q    = lane & 7;     // 16B chunk (channels 8q..8q+7)
    int slot = wv * 8 + (lane >> 3);   // node slot 0..31
    int s = pos_start[g], e = pos_end[g];
    float f0 = 0, f1 = 0, f2 = 0, f3 = 0, f4 = 0, f5 = 0, f6 = 0, f7 = 0;
    for (int n = s + slot; n < e; n += 32) {
        uint4 v = *((const uint4*)(x2b + (long)n * 32) + q);
        f0 += bf2f(v.x & 0xffff); f1 += bf2f(v.x >> 16);
        f2 += bf2f(v.y & 0xffff); f3 += bf2f(v.y >> 16);
        f4 += bf2f(v.z & 0xffff); f5 += bf2f(v.z >> 16);
        f6 += bf2f(v.w & 0xffff); f7 += bf2f(v.w >> 16);
    }
#pragma unroll
    for (int o = 8; o < 64; o <<= 1) {
        f0 += __shfl_xor(f0, o, 64); f1 += __shfl_xor(f1, o, 64);
        f2 += __shfl_xor(f2, o, 64); f3 += __shfl_xor(f3, o, 64);
        f4 += __shfl_xor(f4, o, 64); f5 += __shfl_xor(f5, o, 64);
        f6 += __shfl_xor(f6, o, 64); f7 += __shfl_xor(f7, o, 64);
    }
    if (lane < 8) {          // lane == q here
        part[wv][lane][0] = f0; part[wv][lane][1] = f1;
        part[wv][lane][2] = f2; part[wv][lane][3] = f3;
        part[wv][lane][4] = f4; part[wv][lane][5] = f5;
        part[wv][lane][6] = f6; part[wv][lane][7] = f7;
    }
    __syncthreads();
    if (wv == 0) {
        f0 = part[0][q][0] + part[1][q][0] + part[2][q][0] + part[3][q][0];
        f1 = part[0][q][1] + part[1][q][1] + part[2][q][1] + part[3][q][1];
        f2 = part[0][q][2] + part[1][q][2] + part[2][q][2] + part[3][q][2];
        f3 = part[0][q][3] + part[1][q][3] + part[2][q][3] + part[3][q][3];
        f4 = part[0][q][4] + part[1][q][4] + part[2][q][4] + part[3][q][4];
        f5 = part[0][q][5] + part[1][q][5] + part[2][q][5] + part[3][q][5];
        f6 = part[0][q][6] + part[1][q][6] + part[2][q][6] + part[3][q][6];
        f7 = part[0][q][7] + part[1][q][7] + part[2][q][7] + part[3][q][7];
        float inv = 1.0f / (float)max(e - s, 1);
        f0 *= inv; f1 *= inv; f2 *= inv; f3 *= inv;
        f4 *= inv; f5 *= inv; f6 *= inv; f7 *= inv;
#pragma unroll
        for (int c = 0; c < NCLS; ++c) {
            const float* wr = Wlin + c * HID + q * 8;
            float p = f0 * wr[0] + f1 * wr[1] + f2 * wr[2] + f3 * wr[3] +
                      f4 * wr[4] + f5 * wr[5] + f6 * wr[6] + f7 * wr[7];
            p += __shfl_xor(p, 1, 64);
            p += __shfl_xor(p, 2, 64);
            p += __shfl_xor(p, 4, 64);
            if (lane == 0) out[g * NCLS + c] = p + blin[c];
        }
    }
}

extern "C" void kernel_launch(void* const* d_in, const int* in_sizes, int n_in,
                              void* d_out, int out_size, void* d_ws, size_t ws_size,
                              hipStream_t stream) {
    const int*   tok   = (const int*)d_in[0];
    const int*   eidx  = (const int*)d_in[1];
    const int*   batch = (const int*)d_in[2];
    const float* embed = (const float*)d_in[3];
    const float* W1l   = (const float*)d_in[4];
    const float* b1l   = (const float*)d_in[5];
    const float* W1r   = (const float*)d_in[6];
    const float* W2l   = (const float*)d_in[7];
    const float* b2l   = (const float*)d_in[8];
    const float* W2r   = (const float*)d_in[9];
    const float* Wlin  = (const float*)d_in[10];
    const float* blin  = (const float*)d_in[11];
    float* out = (float*)d_out;

    const int* src = eidx;
    const int* dst = eidx + N_EDGES;

    char* wsp = (char*)d_ws;
    size_t off = 0;
    auto alloc = [&](size_t bytes) -> void* {
        void* p = wsp + off;
        off = (off + bytes + 255) & ~(size_t)255;
        return p;
    };
    // cnt | pstart | pend adjacent -> single memset
    int*   cnt     = (int*)  alloc((size_t)N_NODES * 4);
    int*   pstart  = (int*)  alloc((size_t)N_GRAPHS * 4);
    int*   pend    = (int*)  alloc((size_t)N_GRAPHS * 4);
    unsigned int* bucket = (unsigned int*)alloc((size_t)N_NODES * NB * 4);
    unsigned int* x1b    = (unsigned int*)alloc((size_t)N_NODES * 32 * 4);
    unsigned int* x2b    = (unsigned int*)alloc((size_t)N_NODES * 32 * 4);
    unsigned int* ebufg  = (unsigned int*)alloc((size_t)128 * 32 * 4);
    unsigned int* wb1    = (unsigned int*)alloc((size_t)64 * 64 * 4);
    unsigned int* wb2    = (unsigned int*)alloc((size_t)64 * 64 * 4);

    hipMemsetAsync(cnt, 0, (char*)pend - (char*)cnt + (size_t)N_GRAPHS * 4, stream);

    k_prep_fill<<<(PREP_T + 255) / 256, 256, 0, stream>>>(
        src, dst, tok, cnt, bucket,
        embed, ebufg, batch, pstart, pend, W1l, W1r, wb1, W2l, W2r, wb2);

    // Layer 1: neighbors+self from LDS embed table; 32 nodes / 512-thr block
    k_layer<true, 32><<<(N_NODES + 31) / 32, 512, 0, stream>>>(
        cnt, bucket, tok, ebufg, nullptr, wb1, b1l, (unsigned short*)x1b);
    // Layer 2: neighbors+self from x1b; 16 nodes / 256-thr block (max TLP)
    k_layer<false, 16><<<(N_NODES + 15) / 16, 256, 0, stream>>>(
        cnt, bucket, nullptr, nullptr, x1b, wb2, b2l, (unsigned short*)x2b);

    // Pool + head
    k_pool<<<N_GRAPHS, 256, 0, stream>>>(x2b, pstart, pend, Wlin, blin, out);
}